// Round 4
// baseline (494.164 us; speedup 1.0000x reference)
//
#include <hip/hip_runtime.h>
#include <math.h>

// GaussianCircular: separable 15x15 Gaussian conv, fp32, SAME zero-pad.
// R4: same streaming structure as R3 (thread owns 4 cols x 16-row strip,
// register ring of 15 mid-float4s) but loads are made UNCONDITIONAL:
//   - row bounds handled by clamping the row index and multiplying the mid
//     result by a 0/1 mask, instead of branching around the loads.
//   - full 30-row unroll, so every ring index / emit-condition is static.
// R3's loads sat inside a wave-uniform branch -> in-order issue forced a full
// vmcnt(0) drain every row (30 x ~900cyc exposed latency, waves 94% stalled).
// Unconditional loads let the compiler hoist next rows' loads and emit
// fine-grained vmcnt(N), overlapping load latency with FMA work.
// Nontemporal stores keep d_out from polluting L2 (x halo reuse lives there).

#define RAD   7
#define KS    15
#define ROWS  16              // output rows per strip
#define MROWS (ROWS + 2*RAD)  // 30 mid rows

using f32x4 = __attribute__((ext_vector_type(4))) float;

__global__ __launch_bounds__(256, 4) void gauss_stream2_kernel(
    const float* __restrict__ x,
    const float* __restrict__ sigma_p,
    const float* __restrict__ gain_p,
    float* __restrict__ out,
    int H, int W)
{
    const int strips = H / ROWS;                  // 64
    const int n      = blockIdx.x / strips;
    const int strip  = blockIdx.x - n * strips;
    const int row0   = strip * ROWS;

    const int c0 = threadIdx.x * 4;               // 256 thr * 4 = 1024 = W

    const float* __restrict__ img    = x   + (size_t)n * H * W;
    float*       __restrict__ outimg = out + (size_t)n * H * W;

    // Separable weights: gain*exp(-(i^2+j^2)/2s^2) = gain * w[i] * w[j]
    const float s    = fabsf(sigma_p[0]);
    const float gain = gain_p[0];
    const float inv  = -1.0f / (2.0f * s * s);
    float w[KS];
#pragma unroll
    for (int j = 0; j < KS; ++j) {
        const float d = (float)(j - RAD);
        w[j] = expf(d * d * inv);
    }

    // Column-edge lanes (window [c0-8, c0+11] exits the row): lanes {0,1,254,255}.
    const bool edge = (c0 < 8) || (c0 > W - 12);

    float4 ring[15];   // last 15 mid rows, slot = j % 15 (static after unroll)

#pragma unroll
    for (int j = 0; j < MROWS; ++j) {
        const int gr  = row0 - RAD + j;                    // wanted input row
        const int grc = min(max(gr, 0), H - 1);            // clamped (always valid)
        const float rowmask = (gr == grc) ? 1.0f : 0.0f;   // 0 outside image
        const float* rowp = img + (size_t)grc * W;

        // ---- horizontal pass: 5 overlapping aligned float4 loads (L1 reuse) ----
        float f[20];                                       // cols c0-8 .. c0+11
        if (edge) {
#pragma unroll
            for (int k = 0; k < 20; ++k) {
                const int col = c0 - 8 + k;
                f[k] = (col >= 0 && col < W) ? rowp[col] : 0.0f;
            }
        } else {
            const float4 f0 = *(const float4*)(rowp + c0 - 8);
            const float4 f1 = *(const float4*)(rowp + c0 - 4);
            const float4 f2 = *(const float4*)(rowp + c0);
            const float4 f3 = *(const float4*)(rowp + c0 + 4);
            const float4 f4 = *(const float4*)(rowp + c0 + 8);
            f[0]=f0.x;  f[1]=f0.y;  f[2]=f0.z;  f[3]=f0.w;
            f[4]=f1.x;  f[5]=f1.y;  f[6]=f1.z;  f[7]=f1.w;
            f[8]=f2.x;  f[9]=f2.y;  f[10]=f2.z; f[11]=f2.w;
            f[12]=f3.x; f[13]=f3.y; f[14]=f3.z; f[15]=f3.w;
            f[16]=f4.x; f[17]=f4.y; f[18]=f4.z; f[19]=f4.w;
        }

        float4 mid = make_float4(0.f, 0.f, 0.f, 0.f);
#pragma unroll
        for (int jj = 0; jj < KS; ++jj) {
            const float wv = w[jj];
            mid.x += wv * f[1 + jj];
            mid.y += wv * f[2 + jj];
            mid.z += wv * f[3 + jj];
            mid.w += wv * f[4 + jj];
        }
        mid.x *= rowmask; mid.y *= rowmask; mid.z *= rowmask; mid.w *= rowmask;
        ring[j % 15] = mid;

        // ---- vertical pass: emit output row o = j-14 (condition is static) ----
        if (j >= 2 * RAD) {
            float4 acc = make_float4(0.f, 0.f, 0.f, 0.f);
#pragma unroll
            for (int i = 0; i < KS; ++i) {
                const float wv = w[i];
                const float4 m = ring[(j + 1 + i) % 15];   // static index
                acc.x += wv * m.x; acc.y += wv * m.y;
                acc.z += wv * m.z; acc.w += wv * m.w;
            }
            acc.x *= gain; acc.y *= gain; acc.z *= gain; acc.w *= gain;
            const int o = row0 + j - 2 * RAD;
            float* op = outimg + (size_t)o * W + c0;
            __builtin_nontemporal_store(*(const f32x4*)&acc, (f32x4*)op);
        }
    }
}

extern "C" void kernel_launch(void* const* d_in, const int* in_sizes, int n_in,
                              void* d_out, int out_size, void* d_ws, size_t ws_size,
                              hipStream_t stream) {
    const float* x       = (const float*)d_in[0];
    const float* sigma_p = (const float*)d_in[1];
    const float* gain_p  = (const float*)d_in[2];
    float* out = (float*)d_out;

    const int H = 1024, W = 1024;
    const int N = in_sizes[0] / (H * W);          // 16

    const dim3 grid(N * (H / ROWS));              // 16 * 64 = 1024 blocks
    gauss_stream2_kernel<<<grid, 256, 0, stream>>>(x, sigma_p, gain_p, out, H, W);
}

// Round 5
// 126.918 us; speedup vs baseline: 3.8936x; 3.8936x over previous
//
#include <hip/hip_runtime.h>
#include <math.h>

// GaussianCircular: separable 15x15 Gaussian conv, fp32, SAME zero-pad.
// R5: VERTICAL-FIRST streaming. Each thread owns 4 cols, slides a ring of 15
// INPUT rows (each input float4 loaded exactly once per thread), computes one
// mid row (vertical conv), hands it across lanes through a tiny double-
// buffered LDS row (1040 words, zero-padded 8 each side), one barrier per
// row, then horizontal conv + gain -> nontemporal store.
//   vs R3 (h-first): no 5x overlapping-window reloads, loads unconditional
//   (clamped row + 0/1 mask) so the compiler can hoist/pipeline them.
//   vs R4: NO min-waves launch bound (that forced VGPR=64 -> spill disaster).
// LDS traffic: 6 b128/row/wave; barrier count: 16/block.

#define RAD   7
#define KS    15
#define S     16               // output rows per strip
#define PRE   (2 * RAD)        // 14 prologue rows
#define PADW  8                // zero pad words each side of mid row
#define MIDW  (1024 + 2 * PADW)

using f32x4 = __attribute__((ext_vector_type(4))) float;

__global__ __launch_bounds__(256) void gauss_vfirst_kernel(
    const float* __restrict__ x,
    const float* __restrict__ sigma_p,
    const float* __restrict__ gain_p,
    float* __restrict__ out,
    int H, int W)
{
    __shared__ float smid[2][MIDW];          // 2 x 1040 fp32 = 8320 B

    const int strips = H / S;                // 64
    const int n      = blockIdx.x / strips;
    const int strip  = blockIdx.x - n * strips;
    const int row0   = strip * S;

    const int tid = threadIdx.x;
    const int c0  = tid * 4;                 // 256 thr * 4 = 1024 = W

    const float* __restrict__ img    = x   + (size_t)n * H * W;
    float*       __restrict__ outimg = out + (size_t)n * H * W;

    // Separable weights: gain*exp(-(i^2+j^2)/2s^2) = gain * w[i] * w[j]
    const float s    = fabsf(sigma_p[0]);
    const float gain = gain_p[0];
    const float inv  = -1.0f / (2.0f * s * s);
    float w[KS];
#pragma unroll
    for (int j = 0; j < KS; ++j) {
        const float d = (float)(j - RAD);
        w[j] = expf(d * d * inv);
    }

    // Zero the pads once (read every row, never rewritten; first read is
    // after the k=0 barrier, so no barrier needed here).
    if (tid < PADW) {
        smid[0][tid] = 0.0f;
        smid[1][tid] = 0.0f;
        smid[0][PADW + 1024 + tid] = 0.0f;
        smid[1][PADW + 1024 + tid] = 0.0f;
    }

    // ---- prologue: input rows row0-7 .. row0+6 -> ring slots 0..13 ----
    float4 ring[15];
#pragma unroll
    for (int p = 0; p < PRE; ++p) {
        const int gr  = row0 - RAD + p;
        const int grc = max(gr, 0);                    // only lower clamp here
        const float m = (gr >= 0) ? 1.0f : 0.0f;
        float4 v = *(const float4*)(img + (size_t)grc * W + c0);
        v.x *= m; v.y *= m; v.z *= m; v.w *= m;
        ring[p] = v;
    }

    // ---- main: 16 output rows ----
#pragma unroll
    for (int k = 0; k < S; ++k) {
        // load input row row0+k+7 -> slot (k+14)%15 (unconditional, masked)
        {
            const int gr  = row0 + k + RAD;
            const int grc = min(gr, H - 1);            // only upper clamp here
            const float m = (gr < H) ? 1.0f : 0.0f;
            float4 v = *(const float4*)(img + (size_t)grc * W + c0);
            v.x *= m; v.y *= m; v.z *= m; v.w *= m;
            ring[(k + PRE) % 15] = v;
        }

        // vertical pass: mid row o = row0+k from ring rows o-7..o+7
        float4 mid = make_float4(0.f, 0.f, 0.f, 0.f);
#pragma unroll
        for (int i = 0; i < KS; ++i) {
            const float wv  = w[i];
            const float4 r  = ring[(k + i) % 15];      // static after unroll
            mid.x += wv * r.x; mid.y += wv * r.y;
            mid.z += wv * r.z; mid.w += wv * r.w;
        }

        const int buf = k & 1;
        *(float4*)&smid[buf][PADW + c0] = mid;
        __syncthreads();   // dbuf + 1 barrier/row: iter k+2 write can't pass
                           // barrier(k+1), which is after all iter-k reads.

        // horizontal pass: 5 aligned b128 LDS reads -> window [c0-8, c0+12)
        const float* mp = &smid[buf][c0];              // word c0 = PADW+c0-8
        const float4 f0 = *(const float4*)(mp);
        const float4 f1 = *(const float4*)(mp + 4);
        const float4 f2 = *(const float4*)(mp + 8);
        const float4 f3 = *(const float4*)(mp + 12);
        const float4 f4 = *(const float4*)(mp + 16);
        float f[20] = { f0.x, f0.y, f0.z, f0.w,
                        f1.x, f1.y, f1.z, f1.w,
                        f2.x, f2.y, f2.z, f2.w,
                        f3.x, f3.y, f3.z, f3.w,
                        f4.x, f4.y, f4.z, f4.w };
        float4 acc = make_float4(0.f, 0.f, 0.f, 0.f);
#pragma unroll
        for (int jj = 0; jj < KS; ++jj) {
            const float wv = w[jj];
            acc.x += wv * f[1 + jj];
            acc.y += wv * f[2 + jj];
            acc.z += wv * f[3 + jj];
            acc.w += wv * f[4 + jj];
        }
        acc.x *= gain; acc.y *= gain; acc.z *= gain; acc.w *= gain;

        float* op = outimg + (size_t)(row0 + k) * W + c0;
        __builtin_nontemporal_store(*(const f32x4*)&acc, (f32x4*)op);
    }
}

extern "C" void kernel_launch(void* const* d_in, const int* in_sizes, int n_in,
                              void* d_out, int out_size, void* d_ws, size_t ws_size,
                              hipStream_t stream) {
    const float* x       = (const float*)d_in[0];
    const float* sigma_p = (const float*)d_in[1];
    const float* gain_p  = (const float*)d_in[2];
    float* out = (float*)d_out;

    const int H = 1024, W = 1024;
    const int N = in_sizes[0] / (H * W);               // 16

    const dim3 grid(N * (H / S));                      // 16 * 64 = 1024 blocks
    gauss_vfirst_kernel<<<grid, 256, 0, stream>>>(x, sigma_p, gain_p, out, H, W);
}